// Round 1
// baseline (3467.899 us; speedup 1.0000x reference)
//
#include <hip/hip_runtime.h>
#include <hip/hip_bf16.h>

#define NN 40000
#define NE 512000
#define DD 128
#define RR 8
#define KT 1152   // R*D + D

// ---------------- edge-count (once per call: structure-only) ----------------
__global__ void count_kernel(const int* __restrict__ dst, const int* __restrict__ et,
                             float* __restrict__ cnt) {
  int e = blockIdx.x * blockDim.x + threadIdx.x;
  if (e < NE) atomicAdd(&cnt[dst[e] * RR + et[e]], 1.0f);
}

__global__ void invc_kernel(float* __restrict__ cnt) {
  int i = blockIdx.x * blockDim.x + threadIdx.x;
  if (i < NN * RR) cnt[i] = 1.0f / fmaxf(cnt[i], 1.0f);
}

// ---------------- h0 = prelu(num_x*lin_w + lin_b) + x ----------------
__global__ void init_h_kernel(const float* __restrict__ num_x, const float* __restrict__ x,
                              const float* __restrict__ lin_w, const float* __restrict__ lin_b,
                              const float* __restrict__ a0, float* __restrict__ h) {
  int idx = blockIdx.x * blockDim.x + threadIdx.x;
  if (idx >= NN * DD) return;
  int n = idx >> 7, d = idx & 127;
  float v = num_x[n] * lin_w[d] + lin_b[d];
  v = v >= 0.f ? v : a0[d] * v;
  h[idx] = v + x[idx];
}

// ---------------- W[k][j]: rows 0..1023 = sum_b comp[r,b]*bases[b,i,j]; rows 1024.. = root ----
__global__ void build_w_kernel(const float* __restrict__ bases, const float* __restrict__ comp,
                               const float* __restrict__ root, float* __restrict__ W) {
  int idx = blockIdx.x * blockDim.x + threadIdx.x; // KT*DD
  if (idx >= KT * DD) return;
  int row = idx >> 7, j = idx & 127;
  if (row < RR * DD) {
    int r = row >> 7, i = row & 127;
    float s = 0.f;
#pragma unroll
    for (int b = 0; b < 8; ++b) s += comp[r * 8 + b] * bases[(b * DD + i) * DD + j];
    W[idx] = s;
  } else {
    W[idx] = root[(row - RR * DD) * DD + j];
  }
}

// ---------------- scatter: agg[dst*R+et][:] += h[src][:] ----------------
__global__ void scatter_kernel(const int* __restrict__ src, const int* __restrict__ dst,
                               const int* __restrict__ et, const float* __restrict__ h,
                               float* __restrict__ agg) {
  int e = blockIdx.x * 2 + (threadIdx.x >> 7);
  if (e >= NE) return;
  int d = threadIdx.x & 127;
  int s = src[e];
  int seg = dst[e] * RR + et[e];
  atomicAdd(&agg[(size_t)seg * DD + d], h[s * DD + d]);
}

// ---------------- GEMM: out[n][j] = prelu( X[n,:] @ W[:,j] + bias[j] ) ----------------
// X[n, k] = agg[n][k]*invc[n][k>>7] for k<1024, h[n][k-1024] else.
// tile: 128 nodes x 128 cols, 256 threads, thread tile 8x8.
__global__ __launch_bounds__(256)
void gemm_kernel(const float* __restrict__ agg, const float* __restrict__ h,
                 const float* __restrict__ invc, const float* __restrict__ W,
                 const float* __restrict__ bias, const float* __restrict__ slope,
                 float* __restrict__ out) {
  __shared__ float Xs[16][128];   // [kk][node]
  __shared__ float Ws[16][128];   // [kk][col]
  int n0 = blockIdx.x * 128;
  int tid = threadIdx.x;
  int tcol = (tid & 15) * 8;
  int trow = (tid >> 4) * 8;
  float acc[8][8];
#pragma unroll
  for (int a = 0; a < 8; ++a)
#pragma unroll
    for (int b = 0; b < 8; ++b) acc[a][b] = 0.f;

  for (int kc = 0; kc < KT; kc += 16) {
    // stage W: 16x128 = 512 float4, 2 per thread
#pragma unroll
    for (int i = 0; i < 2; ++i) {
      int vid = tid + i * 256;
      int row = vid >> 5;          // 0..15
      int c4 = (vid & 31) * 4;     // 0..124
      *(float4*)&Ws[row][c4] = *(const float4*)&W[(kc + row) * DD + c4];
    }
    // stage X: 128 nodes x 16 k = 512 float4 (transposed into [kk][node])
#pragma unroll
    for (int i = 0; i < 2; ++i) {
      int vid = tid + i * 256;
      int node = vid >> 2;         // 0..127
      int kq = (vid & 3) * 4;      // 0,4,8,12
      int n = n0 + node;
      int gk = kc + kq;
      float4 xv = make_float4(0.f, 0.f, 0.f, 0.f);
      if (n < NN) {
        if (gk < RR * DD) {
          xv = *(const float4*)&agg[(size_t)n * (RR * DD) + gk];
          float sc = invc[n * RR + (gk >> 7)];
          xv.x *= sc; xv.y *= sc; xv.z *= sc; xv.w *= sc;
        } else {
          xv = *(const float4*)&h[n * DD + (gk - RR * DD)];
        }
      }
      Xs[kq + 0][node] = xv.x;
      Xs[kq + 1][node] = xv.y;
      Xs[kq + 2][node] = xv.z;
      Xs[kq + 3][node] = xv.w;
    }
    __syncthreads();
#pragma unroll
    for (int kk = 0; kk < 16; ++kk) {
      float4 x0 = *(const float4*)&Xs[kk][trow];
      float4 x1 = *(const float4*)&Xs[kk][trow + 4];
      float4 w0 = *(const float4*)&Ws[kk][tcol];
      float4 w1 = *(const float4*)&Ws[kk][tcol + 4];
      float xa[8] = {x0.x, x0.y, x0.z, x0.w, x1.x, x1.y, x1.z, x1.w};
      float wb[8] = {w0.x, w0.y, w0.z, w0.w, w1.x, w1.y, w1.z, w1.w};
#pragma unroll
      for (int a = 0; a < 8; ++a)
#pragma unroll
        for (int b = 0; b < 8; ++b)
          acc[a][b] = fmaf(xa[a], wb[b], acc[a][b]);
    }
    __syncthreads();
  }
#pragma unroll
  for (int a = 0; a < 8; ++a) {
    int n = n0 + trow + a;
    if (n >= NN) break;
#pragma unroll
    for (int b = 0; b < 8; ++b) {
      int j = tcol + b;
      float v = acc[a][b] + bias[j];
      v = v >= 0.f ? v : slope[j] * v;
      out[(size_t)n * DD + j] = v;
    }
  }
}

// ---------------- conv7 weight [1152][3] ----------------
__global__ void build_w7_kernel(const float* __restrict__ bases7, const float* __restrict__ comp7,
                                const float* __restrict__ root7, float* __restrict__ W7) {
  int idx = blockIdx.x * blockDim.x + threadIdx.x; // KT*3
  if (idx >= KT * 3) return;
  int row = idx / 3, c = idx - row * 3;
  if (row < RR * DD) {
    int r = row >> 7, i = row & 127;
    float s = 0.f;
#pragma unroll
    for (int b = 0; b < 8; ++b) s += comp7[r * 8 + b] * bases7[(b * DD + i) * 3 + c];
    W7[idx] = s;
  } else {
    W7[idx] = root7[(row - RR * DD) * 3 + c];
  }
}

// ---------------- conv7 + log_softmax: one wave per node ----------------
__global__ void conv7_kernel(const float* __restrict__ agg, const float* __restrict__ h,
                             const float* __restrict__ invc, const float* __restrict__ W7,
                             const float* __restrict__ bias7, float* __restrict__ out) {
  int gtid = blockIdx.x * blockDim.x + threadIdx.x;
  int wid = gtid >> 6;
  int lane = threadIdx.x & 63;
  if (wid >= NN) return;
  float a0 = 0.f, a1 = 0.f, a2 = 0.f;
  for (int k = lane; k < KT; k += 64) {
    float x;
    if (k < RR * DD) x = agg[(size_t)wid * (RR * DD) + k] * invc[wid * RR + (k >> 7)];
    else x = h[wid * DD + (k - RR * DD)];
    a0 = fmaf(x, W7[k * 3 + 0], a0);
    a1 = fmaf(x, W7[k * 3 + 1], a1);
    a2 = fmaf(x, W7[k * 3 + 2], a2);
  }
#pragma unroll
  for (int o = 32; o > 0; o >>= 1) {
    a0 += __shfl_down(a0, o);
    a1 += __shfl_down(a1, o);
    a2 += __shfl_down(a2, o);
  }
  if (lane == 0) {
    float l0 = a0 + bias7[0], l1 = a1 + bias7[1], l2 = a2 + bias7[2];
    float m = fmaxf(l0, fmaxf(l1, l2));
    float lse = m + logf(expf(l0 - m) + expf(l1 - m) + expf(l2 - m));
    out[wid * 3 + 0] = l0 - lse;
    out[wid * 3 + 1] = l1 - lse;
    out[wid * 3 + 2] = l2 - lse;
  }
}

extern "C" void kernel_launch(void* const* d_in, const int* in_sizes, int n_in,
                              void* d_out, int out_size, void* d_ws, size_t ws_size,
                              hipStream_t stream) {
  const float* num_x  = (const float*)d_in[0];
  const float* x      = (const float*)d_in[1];
  const int*   eidx   = (const int*)d_in[2];
  const int*   etype  = (const int*)d_in[3];
  const float* lin_w  = (const float*)d_in[4];
  const float* lin_b  = (const float*)d_in[5];
  const float* prelu  = (const float*)d_in[6];
  const float* bases  = (const float*)d_in[7];
  const float* comp   = (const float*)d_in[8];
  const float* root   = (const float*)d_in[9];
  const float* bias   = (const float*)d_in[10];
  const float* bases7 = (const float*)d_in[11];
  const float* comp7  = (const float*)d_in[12];
  const float* root7  = (const float*)d_in[13];
  const float* bias7  = (const float*)d_in[14];
  const int* srcv = eidx;
  const int* dstv = eidx + NE;
  float* out = (float*)d_out;

  float* ws = (float*)d_ws;
  float* h    = ws;  ws += (size_t)NN * DD;
  float* h2   = ws;  ws += (size_t)NN * DD;
  float* agg  = ws;  ws += (size_t)NN * RR * DD;
  float* invc = ws;  ws += (size_t)NN * RR;
  float* W    = ws;  ws += (size_t)KT * DD;
  float* W7   = ws;  ws += (size_t)KT * 3;
  // required: ~207 MB of workspace
  if (ws_size < (size_t)((char*)ws - (char*)d_ws)) return;

  hipMemsetAsync(invc, 0, (size_t)NN * RR * sizeof(float), stream);
  count_kernel<<<(NE + 255) / 256, 256, 0, stream>>>(dstv, etype, invc);
  invc_kernel<<<(NN * RR + 255) / 256, 256, 0, stream>>>(invc);
  init_h_kernel<<<(NN * DD + 255) / 256, 256, 0, stream>>>(num_x, x, lin_w, lin_b, prelu, h);

  float* hin = h;
  float* hout = h2;
  for (int layer = 0; layer < 6; ++layer) {
    hipMemsetAsync(agg, 0, (size_t)NN * RR * DD * sizeof(float), stream);
    build_w_kernel<<<(KT * DD + 255) / 256, 256, 0, stream>>>(
        bases + (size_t)layer * 8 * DD * DD, comp + layer * RR * 8,
        root + (size_t)layer * DD * DD, W);
    scatter_kernel<<<NE / 2, 256, 0, stream>>>(srcv, dstv, etype, hin, agg);
    gemm_kernel<<<(NN + 127) / 128, 256, 0, stream>>>(
        agg, hin, invc, W, bias + layer * DD, prelu + (layer + 1) * DD, hout);
    float* t = hin; hin = hout; hout = t;
  }
  hipMemsetAsync(agg, 0, (size_t)NN * RR * DD * sizeof(float), stream);
  build_w7_kernel<<<(KT * 3 + 255) / 256, 256, 0, stream>>>(bases7, comp7, root7, W7);
  scatter_kernel<<<NE / 2, 256, 0, stream>>>(srcv, dstv, etype, hin, agg);
  conv7_kernel<<<(NN + 3) / 4, 256, 0, stream>>>(agg, hin, invc, W7, bias7, out);
}

// Round 2
// 979.860 us; speedup vs baseline: 3.5392x; 3.5392x over previous
//
#include <hip/hip_runtime.h>

typedef unsigned short ushortT;
typedef ushortT ushort8 __attribute__((ext_vector_type(8)));
typedef short bf16x8 __attribute__((ext_vector_type(8)));
typedef float f32x4 __attribute__((ext_vector_type(4)));

#define NN 40000
#define NE 512000
#define DD 128
#define RR 8
#define NSEG (NN * RR)   // 320000
#define KT 1152          // R*D + D
#define NB_SCAN 1250     // NSEG / 256

__device__ __forceinline__ float bf2f(ushortT u) { return __uint_as_float(((unsigned)u) << 16); }
__device__ __forceinline__ ushortT f2bf(float f) {
  unsigned u = __float_as_uint(f);
  unsigned r = (u + 0x7fffu + ((u >> 16) & 1u)) >> 16;   // RNE
  return (ushortT)r;
}

// ---------------- CSR build: count / scan / fill ----------------
__global__ void count_kernel(const int* __restrict__ dst, const int* __restrict__ et,
                             int* __restrict__ cnt) {
  int e = blockIdx.x * 256 + threadIdx.x;
  if (e < NE) atomicAdd(&cnt[dst[e] * RR + et[e]], 1);
}

__global__ void scan1_kernel(const int* __restrict__ cnt, int* __restrict__ offs,
                             int* __restrict__ bsum) {
  __shared__ int s[256];
  int tid = threadIdx.x, gid = blockIdx.x * 256 + tid;
  int v = cnt[gid];            // NSEG = 1250*256 exact
  s[tid] = v; __syncthreads();
  for (int o = 1; o < 256; o <<= 1) {
    int t = (tid >= o) ? s[tid - o] : 0;
    __syncthreads(); s[tid] += t; __syncthreads();
  }
  offs[gid] = s[tid] - v;      // block-local exclusive
  if (tid == 255) bsum[blockIdx.x] = s[255];
}

__global__ void scan2_kernel(int* __restrict__ bsum) {
  __shared__ int s[256];
  __shared__ int carry, tot;
  int tid = threadIdx.x;
  if (tid == 0) carry = 0;
  __syncthreads();
  for (int base = 0; base < NB_SCAN; base += 256) {
    int i = base + tid;
    int v = (i < NB_SCAN) ? bsum[i] : 0;
    s[tid] = v; __syncthreads();
    for (int o = 1; o < 256; o <<= 1) {
      int t = (tid >= o) ? s[tid - o] : 0;
      __syncthreads(); s[tid] += t; __syncthreads();
    }
    if (i < NB_SCAN) bsum[i] = s[tid] - v + carry;
    if (tid == 255) tot = s[255];
    __syncthreads();
    if (tid == 0) carry += tot;
    __syncthreads();
  }
}

__global__ void scan3_kernel(int* __restrict__ offs, const int* __restrict__ bsum,
                             const int* __restrict__ cnt, int* __restrict__ cursor) {
  int gid = blockIdx.x * 256 + threadIdx.x;
  int v = offs[gid] + bsum[blockIdx.x];
  offs[gid] = v;
  cursor[gid] = v;
  if (gid == NSEG - 1) offs[NSEG] = v + cnt[gid];
}

__global__ void fill_kernel(const int* __restrict__ src, const int* __restrict__ dst,
                            const int* __restrict__ et, int* __restrict__ cursor,
                            int* __restrict__ srcs) {
  int e = blockIdx.x * 256 + threadIdx.x;
  if (e >= NE) return;
  int seg = dst[e] * RR + et[e];
  int slot = atomicAdd(&cursor[seg], 1);
  srcs[slot] = src[e];
}

// ---------------- h0 = prelu(num_x*lin_w + lin_b) + x  -> bf16 ----------------
__global__ void init_h_kernel(const float* __restrict__ num_x, const float* __restrict__ x,
                              const float* __restrict__ lin_w, const float* __restrict__ lin_b,
                              const float* __restrict__ a0, ushortT* __restrict__ h) {
  int idx = blockIdx.x * 256 + threadIdx.x;
  if (idx >= NN * DD) return;
  int n = idx >> 7, d = idx & 127;
  float v = fmaf(num_x[n], lin_w[d], lin_b[d]);
  v = v >= 0.f ? v : a0[d] * v;
  h[idx] = f2bf(v + x[idx]);
}

// ---------------- Wt[j][k] bf16 (transposed, K-contiguous) ----------------
__global__ void build_w_kernel(const float* __restrict__ bases, const float* __restrict__ comp,
                               const float* __restrict__ root, ushortT* __restrict__ Wt) {
  int idx = blockIdx.x * 256 + threadIdx.x;  // = j*KT + k
  if (idx >= DD * KT) return;
  int j = idx / KT, k = idx - j * KT;
  float s;
  if (k < RR * DD) {
    int r = k >> 7, i = k & 127;
    s = 0.f;
#pragma unroll
    for (int b = 0; b < 8; ++b) s += comp[r * 8 + b] * bases[(b * DD + i) * DD + j];
  } else {
    s = root[(k - RR * DD) * DD + j];
  }
  Wt[idx] = f2bf(s);
}

// ---------------- aggregation: one wave per (node,rel) segment ----------------
__global__ void agg_kernel(const int* __restrict__ offs, const int* __restrict__ srcs,
                           const ushortT* __restrict__ h, ushortT* __restrict__ Xagg) {
  int gw = (blockIdx.x * 256 + threadIdx.x) >> 6;
  if (gw >= NSEG) return;
  int lane = threadIdx.x & 63;
  int beg = offs[gw], end = offs[gw + 1];
  float inv = (end > beg) ? 1.0f / (float)(end - beg) : 1.0f;
  float a0 = 0.f, a1 = 0.f;
  for (int e = beg; e < end; ++e) {
    int s = srcs[e];
    unsigned v = *(const unsigned*)&h[s * DD + lane * 2];
    a0 += __uint_as_float(v << 16);
    a1 += __uint_as_float(v & 0xffff0000u);
  }
  unsigned r = (unsigned)f2bf(a0 * inv) | ((unsigned)f2bf(a1 * inv) << 16);
  *(unsigned*)&Xagg[(size_t)gw * DD + lane * 2] = r;
}

// ---------------- GEMM: hout = prelu( [Xagg|h] @ Wt^T + bias ), bf16 MFMA ----------------
// BM=64 (625 blocks exact), BN=128, BK=64. 4 waves: wave = 32M x 64N.
__global__ __launch_bounds__(256)
void gemm_kernel(const ushortT* __restrict__ Xagg, const ushortT* __restrict__ h,
                 const ushortT* __restrict__ Wt, const float* __restrict__ bias,
                 const float* __restrict__ slope, ushortT* __restrict__ hout) {
  __shared__ ushortT As[64 * 72];    // pitch 72 bf16 = 144 B (36 dwords -> <=2-way banks)
  __shared__ ushortT Bs[128 * 72];
  int tid = threadIdx.x, lane = tid & 63, wv = tid >> 6;
  int wr = wv >> 1, wc = wv & 1;
  int n0 = blockIdx.x * 64;
  f32x4 acc[2][4];
#pragma unroll
  for (int m = 0; m < 2; ++m)
#pragma unroll
    for (int n = 0; n < 4; ++n) acc[m][n] = (f32x4){0.f, 0.f, 0.f, 0.f};

  for (int kc = 0; kc < KT; kc += 64) {
    const ushortT* Ab;
    int astr;
    if (kc < RR * DD) { Ab = Xagg + (size_t)n0 * 1024 + kc; astr = 1024; }
    else              { Ab = h + n0 * DD + (kc - RR * DD);  astr = DD;   }
    // stage A: 64 rows x 64 bf16 = 512 x 16B chunks
#pragma unroll
    for (int i = 0; i < 2; ++i) {
      int c = tid + i * 256; int r = c >> 3, p = c & 7;
      *(ushort8*)&As[r * 72 + p * 8] = *(const ushort8*)&Ab[r * astr + p * 8];
    }
    // stage B: 128 cols x 64 bf16 (Wt is K-contiguous per col)
#pragma unroll
    for (int i = 0; i < 4; ++i) {
      int c = tid + i * 256; int col = c >> 3, p = c & 7;
      *(ushort8*)&Bs[col * 72 + p * 8] = *(const ushort8*)&Wt[col * KT + kc + p * 8];
    }
    __syncthreads();
#pragma unroll
    for (int kk = 0; kk < 2; ++kk) {
      int koff = kk * 32 + (lane >> 4) * 8;
      bf16x8 a[2], b[4];
#pragma unroll
      for (int m = 0; m < 2; ++m)
        a[m] = *(const bf16x8*)&As[(wr * 32 + m * 16 + (lane & 15)) * 72 + koff];
#pragma unroll
      for (int n = 0; n < 4; ++n)
        b[n] = *(const bf16x8*)&Bs[(wc * 64 + n * 16 + (lane & 15)) * 72 + koff];
#pragma unroll
      for (int m = 0; m < 2; ++m)
#pragma unroll
        for (int n = 0; n < 4; ++n)
          acc[m][n] = __builtin_amdgcn_mfma_f32_16x16x32_bf16(a[m], b[n], acc[m][n], 0, 0, 0);
    }
    __syncthreads();
  }
  // epilogue: D layout col=lane&15, row=(lane>>4)*4+reg  [m89]
#pragma unroll
  for (int m = 0; m < 2; ++m) {
    int row = n0 + wr * 32 + m * 16 + (lane >> 4) * 4;
#pragma unroll
    for (int n = 0; n < 4; ++n) {
      int col = wc * 64 + n * 16 + (lane & 15);
      float bcol = bias[col], scol = slope[col];
#pragma unroll
      for (int q = 0; q < 4; ++q) {
        float v = acc[m][n][q] + bcol;
        v = v >= 0.f ? v : scol * v;
        hout[(size_t)(row + q) * DD + col] = f2bf(v);
      }
    }
  }
}

// ---------------- conv7 weight [1152][3] fp32 ----------------
__global__ void build_w7_kernel(const float* __restrict__ bases7, const float* __restrict__ comp7,
                                const float* __restrict__ root7, float* __restrict__ W7) {
  int idx = blockIdx.x * 256 + threadIdx.x;
  if (idx >= KT * 3) return;
  int row = idx / 3, c = idx - row * 3;
  if (row < RR * DD) {
    int r = row >> 7, i = row & 127;
    float s = 0.f;
#pragma unroll
    for (int b = 0; b < 8; ++b) s += comp7[r * 8 + b] * bases7[(b * DD + i) * 3 + c];
    W7[idx] = s;
  } else {
    W7[idx] = root7[(row - RR * DD) * 3 + c];
  }
}

// ---------------- conv7 + log_softmax: one wave per node ----------------
__global__ void conv7_kernel(const ushortT* __restrict__ Xagg, const ushortT* __restrict__ h,
                             const float* __restrict__ W7, const float* __restrict__ bias7,
                             float* __restrict__ out) {
  int gw = (blockIdx.x * 256 + threadIdx.x) >> 6;
  if (gw >= NN) return;
  int lane = threadIdx.x & 63;
  float a0 = 0.f, a1 = 0.f, a2 = 0.f;
#pragma unroll
  for (int i = 0; i < 2; ++i) {
    int k0 = i * 512 + lane * 8;
    ushort8 v = *(const ushort8*)&Xagg[(size_t)gw * 1024 + k0];
#pragma unroll
    for (int j = 0; j < 8; ++j) {
      float xx = bf2f(v[j]);
      const float* w = &W7[(k0 + j) * 3];
      a0 = fmaf(xx, w[0], a0); a1 = fmaf(xx, w[1], a1); a2 = fmaf(xx, w[2], a2);
    }
  }
  {
    unsigned v = *(const unsigned*)&h[gw * DD + lane * 2];
    float x0 = __uint_as_float(v << 16), x1 = __uint_as_float(v & 0xffff0000u);
    int k0 = 1024 + lane * 2;
    const float* w0 = &W7[k0 * 3];
    const float* w1 = &W7[(k0 + 1) * 3];
    a0 = fmaf(x0, w0[0], a0); a1 = fmaf(x0, w0[1], a1); a2 = fmaf(x0, w0[2], a2);
    a0 = fmaf(x1, w1[0], a0); a1 = fmaf(x1, w1[1], a1); a2 = fmaf(x1, w1[2], a2);
  }
#pragma unroll
  for (int o = 32; o > 0; o >>= 1) {
    a0 += __shfl_down(a0, o);
    a1 += __shfl_down(a1, o);
    a2 += __shfl_down(a2, o);
  }
  if (lane == 0) {
    float l0 = a0 + bias7[0], l1 = a1 + bias7[1], l2 = a2 + bias7[2];
    float m = fmaxf(l0, fmaxf(l1, l2));
    float lse = m + logf(expf(l0 - m) + expf(l1 - m) + expf(l2 - m));
    out[gw * 3 + 0] = l0 - lse;
    out[gw * 3 + 1] = l1 - lse;
    out[gw * 3 + 2] = l2 - lse;
  }
}

extern "C" void kernel_launch(void* const* d_in, const int* in_sizes, int n_in,
                              void* d_out, int out_size, void* d_ws, size_t ws_size,
                              hipStream_t stream) {
  const float* num_x  = (const float*)d_in[0];
  const float* x      = (const float*)d_in[1];
  const int*   eidx   = (const int*)d_in[2];
  const int*   etype  = (const int*)d_in[3];
  const float* lin_w  = (const float*)d_in[4];
  const float* lin_b  = (const float*)d_in[5];
  const float* prelu  = (const float*)d_in[6];
  const float* bases  = (const float*)d_in[7];
  const float* comp   = (const float*)d_in[8];
  const float* root   = (const float*)d_in[9];
  const float* bias   = (const float*)d_in[10];
  const float* bases7 = (const float*)d_in[11];
  const float* comp7  = (const float*)d_in[12];
  const float* root7  = (const float*)d_in[13];
  const float* bias7  = (const float*)d_in[14];
  const int* srcv = eidx;
  const int* dstv = eidx + NE;
  float* out = (float*)d_out;

  char* p = (char*)d_ws;
  auto alloc = [&](size_t bytes) { char* q = p; p += (bytes + 255) & ~(size_t)255; return q; };
  int*     counts = (int*)alloc((size_t)NSEG * 4);
  int*     offs   = (int*)alloc((size_t)(NSEG + 1) * 4);
  int*     cursor = (int*)alloc((size_t)NSEG * 4);
  int*     bsum   = (int*)alloc((size_t)NB_SCAN * 4);
  int*     srcs   = (int*)alloc((size_t)NE * 4);
  ushortT* h0     = (ushortT*)alloc((size_t)NN * DD * 2);
  ushortT* h1     = (ushortT*)alloc((size_t)NN * DD * 2);
  ushortT* Xagg   = (ushortT*)alloc((size_t)NN * 1024 * 2);
  ushortT* Wt     = (ushortT*)alloc((size_t)DD * KT * 2);
  float*   W7     = (float*)alloc((size_t)KT * 3 * 4);
  if (ws_size < (size_t)(p - (char*)d_ws)) return;  // ~109 MB needed

  // CSR build (structure-only, once per call)
  hipMemsetAsync(counts, 0, (size_t)NSEG * 4, stream);
  count_kernel<<<NE / 256, 256, 0, stream>>>(dstv, etype, counts);
  scan1_kernel<<<NB_SCAN, 256, 0, stream>>>(counts, offs, bsum);
  scan2_kernel<<<1, 256, 0, stream>>>(bsum);
  scan3_kernel<<<NB_SCAN, 256, 0, stream>>>(offs, bsum, counts, cursor);
  fill_kernel<<<NE / 256, 256, 0, stream>>>(srcv, dstv, etype, cursor, srcs);

  init_h_kernel<<<(NN * DD + 255) / 256, 256, 0, stream>>>(num_x, x, lin_w, lin_b, prelu, h0);

  ushortT* hin = h0;
  ushortT* hout = h1;
  for (int layer = 0; layer < 6; ++layer) {
    build_w_kernel<<<(DD * KT + 255) / 256, 256, 0, stream>>>(
        bases + (size_t)layer * 8 * DD * DD, comp + layer * RR * 8,
        root + (size_t)layer * DD * DD, Wt);
    agg_kernel<<<NSEG / 4, 256, 0, stream>>>(offs, srcs, hin, Xagg);
    gemm_kernel<<<NN / 64, 256, 0, stream>>>(Xagg, hin, Wt, bias + layer * DD,
                                             prelu + (layer + 1) * DD, hout);
    ushortT* t = hin; hin = hout; hout = t;
  }
  build_w7_kernel<<<(KT * 3 + 255) / 256, 256, 0, stream>>>(bases7, comp7, root7, W7);
  agg_kernel<<<NSEG / 4, 256, 0, stream>>>(offs, srcs, hin, Xagg);
  conv7_kernel<<<NN / 4, 256, 0, stream>>>(Xagg, hin, W7, bias7, out);
}

// Round 3
// 507.993 us; speedup vs baseline: 6.8267x; 1.9289x over previous
//
#include <hip/hip_runtime.h>

typedef unsigned short ushortT;
typedef ushortT ushort8 __attribute__((ext_vector_type(8)));
typedef short bf16x8 __attribute__((ext_vector_type(8)));
typedef float f32x4 __attribute__((ext_vector_type(4)));

#define NN 40000
#define NE 512000
#define DD 128
#define RR 8
#define NSEG (NN * RR)   // 320000
#define KT 1152          // R*D + D
#define NB_SCAN 1250     // NSEG / 256

__device__ __forceinline__ float bf2f(ushortT u) { return __uint_as_float(((unsigned)u) << 16); }
__device__ __forceinline__ ushortT f2bf(float f) {
  unsigned u = __float_as_uint(f);
  unsigned r = (u + 0x7fffu + ((u >> 16) & 1u)) >> 16;   // RNE
  return (ushortT)r;
}

// ---------------- CSR build: count / scan / fill ----------------
__global__ void count_kernel(const int* __restrict__ dst, const int* __restrict__ et,
                             int* __restrict__ cnt) {
  int e = blockIdx.x * 256 + threadIdx.x;
  if (e < NE) atomicAdd(&cnt[dst[e] * RR + et[e]], 1);
}

__global__ void scan1_kernel(const int* __restrict__ cnt, int* __restrict__ offs,
                             int* __restrict__ bsum) {
  __shared__ int s[256];
  int tid = threadIdx.x, gid = blockIdx.x * 256 + tid;
  int v = cnt[gid];            // NSEG = 1250*256 exact
  s[tid] = v; __syncthreads();
  for (int o = 1; o < 256; o <<= 1) {
    int t = (tid >= o) ? s[tid - o] : 0;
    __syncthreads(); s[tid] += t; __syncthreads();
  }
  offs[gid] = s[tid] - v;      // block-local exclusive
  if (tid == 255) bsum[blockIdx.x] = s[255];
}

__global__ void scan2_kernel(int* __restrict__ bsum) {
  __shared__ int s[256];
  __shared__ int carry, tot;
  int tid = threadIdx.x;
  if (tid == 0) carry = 0;
  __syncthreads();
  for (int base = 0; base < NB_SCAN; base += 256) {
    int i = base + tid;
    int v = (i < NB_SCAN) ? bsum[i] : 0;
    s[tid] = v; __syncthreads();
    for (int o = 1; o < 256; o <<= 1) {
      int t = (tid >= o) ? s[tid - o] : 0;
      __syncthreads(); s[tid] += t; __syncthreads();
    }
    if (i < NB_SCAN) bsum[i] = s[tid] - v + carry;
    if (tid == 255) tot = s[255];
    __syncthreads();
    if (tid == 0) carry += tot;
    __syncthreads();
  }
}

__global__ void scan3_kernel(int* __restrict__ offs, const int* __restrict__ bsum,
                             const int* __restrict__ cnt, int* __restrict__ cursor) {
  int gid = blockIdx.x * 256 + threadIdx.x;
  int v = offs[gid] + bsum[blockIdx.x];
  offs[gid] = v;
  cursor[gid] = v;
  if (gid == NSEG - 1) offs[NSEG] = v + cnt[gid];
}

__global__ void fill_kernel(const int* __restrict__ src, const int* __restrict__ dst,
                            const int* __restrict__ et, int* __restrict__ cursor,
                            int* __restrict__ srcs) {
  int e = blockIdx.x * 256 + threadIdx.x;
  if (e >= NE) return;
  int seg = dst[e] * RR + et[e];
  int slot = atomicAdd(&cursor[seg], 1);
  srcs[slot] = src[e];
}

// ---------------- h0 = prelu(num_x*lin_w + lin_b) + x  -> bf16 ----------------
__global__ void init_h_kernel(const float* __restrict__ num_x, const float* __restrict__ x,
                              const float* __restrict__ lin_w, const float* __restrict__ lin_b,
                              const float* __restrict__ a0, ushortT* __restrict__ h) {
  int idx = blockIdx.x * 256 + threadIdx.x;
  if (idx >= NN * DD) return;
  int n = idx >> 7, d = idx & 127;
  float v = fmaf(num_x[n], lin_w[d], lin_b[d]);
  v = v >= 0.f ? v : a0[d] * v;
  h[idx] = f2bf(v + x[idx]);
}

// ---------------- Wt[j][k] bf16 (transposed, K-contiguous) ----------------
__global__ void build_w_kernel(const float* __restrict__ bases, const float* __restrict__ comp,
                               const float* __restrict__ root, ushortT* __restrict__ Wt) {
  int idx = blockIdx.x * 256 + threadIdx.x;  // = j*KT + k
  if (idx >= DD * KT) return;
  int j = idx / KT, k = idx - j * KT;
  float s;
  if (k < RR * DD) {
    int r = k >> 7, i = k & 127;
    s = 0.f;
#pragma unroll
    for (int b = 0; b < 8; ++b) s += comp[r * 8 + b] * bases[(b * DD + i) * DD + j];
  } else {
    s = root[(k - RR * DD) * DD + j];
  }
  Wt[idx] = f2bf(s);
}

// ---------------- aggregation: 16 lanes per segment, 4 segments per wave ----------------
__global__ __launch_bounds__(256)
void agg_kernel(const int* __restrict__ offs, const int* __restrict__ srcs,
                const ushortT* __restrict__ h, ushortT* __restrict__ Xagg) {
  int seg = blockIdx.x * 16 + (threadIdx.x >> 4);   // NSEG/16 blocks exact
  int l = threadIdx.x & 15;
  int beg = offs[seg], end = offs[seg + 1];
  float a[8] = {0.f, 0.f, 0.f, 0.f, 0.f, 0.f, 0.f, 0.f};
  int e = beg;
  for (; e + 2 <= end; e += 2) {
    int s0 = srcs[e], s1 = srcs[e + 1];
    ushort8 v0 = *(const ushort8*)&h[(size_t)s0 * DD + l * 8];
    ushort8 v1 = *(const ushort8*)&h[(size_t)s1 * DD + l * 8];
#pragma unroll
    for (int j = 0; j < 8; ++j) a[j] += bf2f(v0[j]) + bf2f(v1[j]);
  }
  if (e < end) {
    int s0 = srcs[e];
    ushort8 v0 = *(const ushort8*)&h[(size_t)s0 * DD + l * 8];
#pragma unroll
    for (int j = 0; j < 8; ++j) a[j] += bf2f(v0[j]);
  }
  float inv = (end > beg) ? 1.0f / (float)(end - beg) : 1.0f;
  ushort8 r;
#pragma unroll
  for (int j = 0; j < 8; ++j) r[j] = f2bf(a[j] * inv);
  *(ushort8*)&Xagg[(size_t)seg * DD + l * 8] = r;
}

// ---------------- GEMM: hout = prelu( [Xagg|h] @ Wt^T + bias ), bf16 MFMA ----------------
// BM=64 (625 blocks exact), BN=128, BK=64. 4 waves: wave = 32M x 64N.
// Staging: global_load_lds width-16, linear LDS [row][64] with st-style XOR swizzle
// applied on the pre-swizzled GLOBAL source chunk and on the ds_read address (rule #21c).
__global__ __launch_bounds__(256)
void gemm_kernel(const ushortT* __restrict__ Xagg, const ushortT* __restrict__ h,
                 const ushortT* __restrict__ Wt, const float* __restrict__ bias,
                 const float* __restrict__ slope, ushortT* __restrict__ hout) {
  __shared__ ushortT As[64 * 64];     // 8 KB, row pitch 128 B
  __shared__ ushortT Bs[128 * 64];    // 16 KB
  int tid = threadIdx.x, lane = tid & 63, wv = tid >> 6;
  int wr = wv >> 1, wc = wv & 1;
  int n0 = blockIdx.x * 64;
  int l8 = lane >> 3;     // 0..7: row-in-issue
  int lp = lane & 7;      // 0..7: dest 16B chunk slot
  f32x4 acc[2][4];
#pragma unroll
  for (int m = 0; m < 2; ++m)
#pragma unroll
    for (int n = 0; n < 4; ++n) acc[m][n] = (f32x4){0.f, 0.f, 0.f, 0.f};

  for (int kc = 0; kc < KT; kc += 64) {
    // ---- stage A: wave wv stages rows wv*16 .. wv*16+15, 2 issues of 8 rows ----
#pragma unroll
    for (int j = 0; j < 2; ++j) {
      int row = wv * 16 + j * 8 + l8;
      int p = lp ^ (row & 7);                 // pre-swizzled source chunk
      const ushortT* g;
      if (kc < RR * DD) g = Xagg + (size_t)(n0 + row) * 1024 + kc + p * 8;
      else              g = h + (size_t)(n0 + row) * DD + (kc - RR * DD) + p * 8;
      __builtin_amdgcn_global_load_lds(
          (const __attribute__((address_space(1))) void*)g,
          (__attribute__((address_space(3))) void*)&As[(wv * 16 + j * 8) * 64], 16, 0, 0);
    }
    // ---- stage B: wave wv stages cols wv*32 .. wv*32+31, 4 issues of 8 cols ----
#pragma unroll
    for (int j = 0; j < 4; ++j) {
      int col = wv * 32 + j * 8 + l8;
      int p = lp ^ (col & 7);
      const ushortT* g = Wt + (size_t)col * KT + kc + p * 8;
      __builtin_amdgcn_global_load_lds(
          (const __attribute__((address_space(1))) void*)g,
          (__attribute__((address_space(3))) void*)&Bs[(wv * 32 + j * 8) * 64], 16, 0, 0);
    }
    __syncthreads();   // compiler drains vmcnt(0) before s_barrier
#pragma unroll
    for (int kk = 0; kk < 2; ++kk) {
      int ko2 = kk * 64 + (lane >> 4) * 16;   // byte offset of k within row
      bf16x8 a[2], b[4];
#pragma unroll
      for (int m = 0; m < 2; ++m) {
        int row = wr * 32 + m * 16 + (lane & 15);
        int off = ((row << 7) + ko2) ^ ((row & 7) << 4);
        a[m] = *(const bf16x8*)((const char*)As + off);
      }
#pragma unroll
      for (int n = 0; n < 4; ++n) {
        int col = wc * 64 + n * 16 + (lane & 15);
        int off = ((col << 7) + ko2) ^ ((col & 7) << 4);
        b[n] = *(const bf16x8*)((const char*)Bs + off);
      }
#pragma unroll
      for (int m = 0; m < 2; ++m)
#pragma unroll
        for (int n = 0; n < 4; ++n)
          acc[m][n] = __builtin_amdgcn_mfma_f32_16x16x32_bf16(a[m], b[n], acc[m][n], 0, 0, 0);
    }
    __syncthreads();
  }
  // epilogue: D layout col=lane&15, row=(lane>>4)*4+reg  [m89]
#pragma unroll
  for (int m = 0; m < 2; ++m) {
    int row = n0 + wr * 32 + m * 16 + (lane >> 4) * 4;
#pragma unroll
    for (int n = 0; n < 4; ++n) {
      int col = wc * 64 + n * 16 + (lane & 15);
      float bcol = bias[col], scol = slope[col];
#pragma unroll
      for (int q = 0; q < 4; ++q) {
        float v = acc[m][n][q] + bcol;
        v = v >= 0.f ? v : scol * v;
        hout[(size_t)(row + q) * DD + col] = f2bf(v);
      }
    }
  }
}

// ---------------- conv7 weight [1152][3] fp32 ----------------
__global__ void build_w7_kernel(const float* __restrict__ bases7, const float* __restrict__ comp7,
                                const float* __restrict__ root7, float* __restrict__ W7) {
  int idx = blockIdx.x * 256 + threadIdx.x;
  if (idx >= KT * 3) return;
  int row = idx / 3, c = idx - row * 3;
  if (row < RR * DD) {
    int r = row >> 7, i = row & 127;
    float s = 0.f;
#pragma unroll
    for (int b = 0; b < 8; ++b) s += comp7[r * 8 + b] * bases7[(b * DD + i) * 3 + c];
    W7[idx] = s;
  } else {
    W7[idx] = root7[(row - RR * DD) * 3 + c];
  }
}

// ---------------- conv7 + log_softmax: one wave per node ----------------
__global__ void conv7_kernel(const ushortT* __restrict__ Xagg, const ushortT* __restrict__ h,
                             const float* __restrict__ W7, const float* __restrict__ bias7,
                             float* __restrict__ out) {
  int gw = (blockIdx.x * 256 + threadIdx.x) >> 6;
  if (gw >= NN) return;
  int lane = threadIdx.x & 63;
  float a0 = 0.f, a1 = 0.f, a2 = 0.f;
#pragma unroll
  for (int i = 0; i < 2; ++i) {
    int k0 = i * 512 + lane * 8;
    ushort8 v = *(const ushort8*)&Xagg[(size_t)gw * 1024 + k0];
#pragma unroll
    for (int j = 0; j < 8; ++j) {
      float xx = bf2f(v[j]);
      const float* w = &W7[(k0 + j) * 3];
      a0 = fmaf(xx, w[0], a0); a1 = fmaf(xx, w[1], a1); a2 = fmaf(xx, w[2], a2);
    }
  }
  {
    unsigned v = *(const unsigned*)&h[gw * DD + lane * 2];
    float x0 = __uint_as_float(v << 16), x1 = __uint_as_float(v & 0xffff0000u);
    int k0 = 1024 + lane * 2;
    const float* w0 = &W7[k0 * 3];
    const float* w1 = &W7[(k0 + 1) * 3];
    a0 = fmaf(x0, w0[0], a0); a1 = fmaf(x0, w0[1], a1); a2 = fmaf(x0, w0[2], a2);
    a0 = fmaf(x1, w1[0], a0); a1 = fmaf(x1, w1[1], a1); a2 = fmaf(x1, w1[2], a2);
  }
#pragma unroll
  for (int o = 32; o > 0; o >>= 1) {
    a0 += __shfl_down(a0, o);
    a1 += __shfl_down(a1, o);
    a2 += __shfl_down(a2, o);
  }
  if (lane == 0) {
    float l0 = a0 + bias7[0], l1 = a1 + bias7[1], l2 = a2 + bias7[2];
    float m = fmaxf(l0, fmaxf(l1, l2));
    float lse = m + logf(expf(l0 - m) + expf(l1 - m) + expf(l2 - m));
    out[gw * 3 + 0] = l0 - lse;
    out[gw * 3 + 1] = l1 - lse;
    out[gw * 3 + 2] = l2 - lse;
  }
}

extern "C" void kernel_launch(void* const* d_in, const int* in_sizes, int n_in,
                              void* d_out, int out_size, void* d_ws, size_t ws_size,
                              hipStream_t stream) {
  const float* num_x  = (const float*)d_in[0];
  const float* x      = (const float*)d_in[1];
  const int*   eidx   = (const int*)d_in[2];
  const int*   etype  = (const int*)d_in[3];
  const float* lin_w  = (const float*)d_in[4];
  const float* lin_b  = (const float*)d_in[5];
  const float* prelu  = (const float*)d_in[6];
  const float* bases  = (const float*)d_in[7];
  const float* comp   = (const float*)d_in[8];
  const float* root   = (const float*)d_in[9];
  const float* bias   = (const float*)d_in[10];
  const float* bases7 = (const float*)d_in[11];
  const float* comp7  = (const float*)d_in[12];
  const float* root7  = (const float*)d_in[13];
  const float* bias7  = (const float*)d_in[14];
  const int* srcv = eidx;
  const int* dstv = eidx + NE;
  float* out = (float*)d_out;

  char* p = (char*)d_ws;
  auto alloc = [&](size_t bytes) { char* q = p; p += (bytes + 255) & ~(size_t)255; return q; };
  int*     counts = (int*)alloc((size_t)NSEG * 4);
  int*     offs   = (int*)alloc((size_t)(NSEG + 1) * 4);
  int*     cursor = (int*)alloc((size_t)NSEG * 4);
  int*     bsum   = (int*)alloc((size_t)NB_SCAN * 4);
  int*     srcs   = (int*)alloc((size_t)NE * 4);
  ushortT* h0     = (ushortT*)alloc((size_t)NN * DD * 2);
  ushortT* h1     = (ushortT*)alloc((size_t)NN * DD * 2);
  ushortT* Xagg   = (ushortT*)alloc((size_t)NN * 1024 * 2);
  ushortT* Wt     = (ushortT*)alloc((size_t)DD * KT * 2);
  float*   W7     = (float*)alloc((size_t)KT * 3 * 4);
  if (ws_size < (size_t)(p - (char*)d_ws)) return;  // ~109 MB needed

  // CSR build (structure-only, once per call)
  hipMemsetAsync(counts, 0, (size_t)NSEG * 4, stream);
  count_kernel<<<NE / 256, 256, 0, stream>>>(dstv, etype, counts);
  scan1_kernel<<<NB_SCAN, 256, 0, stream>>>(counts, offs, bsum);
  scan2_kernel<<<1, 256, 0, stream>>>(bsum);
  scan3_kernel<<<NB_SCAN, 256, 0, stream>>>(offs, bsum, counts, cursor);
  fill_kernel<<<NE / 256, 256, 0, stream>>>(srcv, dstv, etype, cursor, srcs);

  init_h_kernel<<<(NN * DD + 255) / 256, 256, 0, stream>>>(num_x, x, lin_w, lin_b, prelu, h0);

  ushortT* hin = h0;
  ushortT* hout = h1;
  for (int layer = 0; layer < 6; ++layer) {
    build_w_kernel<<<(DD * KT + 255) / 256, 256, 0, stream>>>(
        bases + (size_t)layer * 8 * DD * DD, comp + layer * RR * 8,
        root + (size_t)layer * DD * DD, Wt);
    agg_kernel<<<NSEG / 16, 256, 0, stream>>>(offs, srcs, hin, Xagg);
    gemm_kernel<<<NN / 64, 256, 0, stream>>>(Xagg, hin, Wt, bias + layer * DD,
                                             prelu + (layer + 1) * DD, hout);
    ushortT* t = hin; hin = hout; hout = t;
  }
  build_w7_kernel<<<(KT * 3 + 255) / 256, 256, 0, stream>>>(bases7, comp7, root7, W7);
  agg_kernel<<<NSEG / 16, 256, 0, stream>>>(offs, srcs, hin, Xagg);
  conv7_kernel<<<NN / 4, 256, 0, stream>>>(Xagg, hin, W7, bias7, out);
}